// Round 1
// baseline (3027.388 us; speedup 1.0000x reference)
//
#include <hip/hip_runtime.h>
#include <cstdint>
#include <cstddef>

#define D_DIM 256
#define T_DIM 512
#define B_DIM 128
#define S_DIM 512

// C[M,N] = A[M,K] @ B[N,K]^T (+bias1+bias2). If ids!=nullptr, A row m = emb[ids[m]].
// 256 threads, 128x128 tile, 8x8 microtile, K-chunk 16.
__global__ __launch_bounds__(256, 2)
void gemm_bt(const float* __restrict__ A, const float* __restrict__ Bm,
             float* __restrict__ C,
             const float* __restrict__ bias1, const float* __restrict__ bias2,
             const int* __restrict__ ids, const float* __restrict__ emb,
             int M, int N, int K)
{
    __shared__ float As[16][128];
    __shared__ float Bs[16][128];
    const int tid = threadIdx.x;
    const int m0 = blockIdx.x * 128;
    const int n0 = blockIdx.y * 128;
    const int tx = tid & 15;   // N direction
    const int ty = tid >> 4;   // M direction

    float acc[8][8];
#pragma unroll
    for (int i = 0; i < 8; ++i)
#pragma unroll
        for (int j = 0; j < 8; ++j) acc[i][j] = 0.0f;

    for (int kc = 0; kc < K; kc += 16) {
#pragma unroll
        for (int p = 0; p < 2; ++p) {
            int f   = tid + p * 256;   // 0..511
            int row = f >> 2;          // 0..127
            int kq  = f & 3;           // which float4 in the 16-wide k chunk
            // A tile (optionally gathered through embedding table)
            int gm = m0 + row;
            const float* arow = ids ? (emb + (size_t)ids[gm] * K)
                                    : (A + (size_t)gm * K);
            float4 v = *(const float4*)(arow + kc + kq * 4);
            As[kq * 4 + 0][row] = v.x;
            As[kq * 4 + 1][row] = v.y;
            As[kq * 4 + 2][row] = v.z;
            As[kq * 4 + 3][row] = v.w;
            // B tile
            const float* brow = Bm + (size_t)(n0 + row) * K;
            float4 w = *(const float4*)(brow + kc + kq * 4);
            Bs[kq * 4 + 0][row] = w.x;
            Bs[kq * 4 + 1][row] = w.y;
            Bs[kq * 4 + 2][row] = w.z;
            Bs[kq * 4 + 3][row] = w.w;
        }
        __syncthreads();
#pragma unroll
        for (int k = 0; k < 16; ++k) {
            float a[8], b[8];
            *(float4*)&a[0] = *(const float4*)&As[k][ty * 8];
            *(float4*)&a[4] = *(const float4*)&As[k][ty * 8 + 4];
            *(float4*)&b[0] = *(const float4*)&Bs[k][tx * 8];
            *(float4*)&b[4] = *(const float4*)&Bs[k][tx * 8 + 4];
#pragma unroll
            for (int i = 0; i < 8; ++i)
#pragma unroll
                for (int j = 0; j < 8; ++j) acc[i][j] += a[i] * b[j];
        }
        __syncthreads();
    }

    // epilogue: bias + store
    float bv[8];
#pragma unroll
    for (int j = 0; j < 8; ++j) {
        int gn = n0 + tx * 8 + j;
        float v = 0.0f;
        if (bias1) v += bias1[gn];
        if (bias2) v += bias2[gn];
        bv[j] = v;
    }
#pragma unroll
    for (int i = 0; i < 8; ++i) {
        int gm = m0 + ty * 8 + i;
        float* crow = C + (size_t)gm * N + n0 + tx * 8;
        float4 v0 = make_float4(acc[i][0] + bv[0], acc[i][1] + bv[1],
                                acc[i][2] + bv[2], acc[i][3] + bv[3]);
        float4 v1 = make_float4(acc[i][4] + bv[4], acc[i][5] + bv[5],
                                acc[i][6] + bv[6], acc[i][7] + bv[7]);
        *(float4*)(crow)     = v0;
        *(float4*)(crow + 4) = v1;
    }
}

// Elman recurrence for one layer. One block per batch element; thread d owns
// output unit d and keeps W_hh[d, 0:256] resident in 256 VGPRs (fp32 W_hh is
// 256 KB -> does not fit LDS; streaming from LDS would be ~2x the VALU cost).
// h_{t-1} lives in LDS (same-address broadcast reads are conflict-free).
__global__ __launch_bounds__(256, 1)
void rnn_scan(const float* __restrict__ pre, const float* __restrict__ Whh,
              float* __restrict__ hout)
{
    const int b   = blockIdx.x;
    const int tid = threadIdx.x;

    float4 wv[64];
    const float4* wrow = (const float4*)(Whh + (size_t)tid * D_DIM);
#pragma unroll
    for (int j = 0; j < 64; ++j) wv[j] = wrow[j];

    __shared__ float hs[D_DIM];
    hs[tid] = 0.0f;

    const float* prow  = pre  + (size_t)b * T_DIM * D_DIM;
    float*       horow = hout + (size_t)b * T_DIM * D_DIM;

    float cur = prow[tid];   // pre for t=0 (prefetched)
    __syncthreads();

    for (int t = 0; t < T_DIM; ++t) {
        float nxt = 0.0f;
        if (t + 1 < T_DIM) nxt = prow[(size_t)(t + 1) * D_DIM + tid];  // prefetch

        float acc = cur;
#pragma unroll
        for (int j = 0; j < 64; ++j) {
            float4 hv = *(const float4*)&hs[4 * j];
            acc += wv[j].x * hv.x + wv[j].y * hv.y +
                   wv[j].z * hv.z + wv[j].w * hv.w;
        }
        float hn = tanhf(acc);

        __syncthreads();               // all lanes done reading hs
        hs[tid] = hn;
        horow[(size_t)t * D_DIM + tid] = hn;
        cur = nxt;
        __syncthreads();               // hs updated for next step
    }
}

extern "C" void kernel_launch(void* const* d_in, const int* in_sizes, int n_in,
                              void* d_out, int out_size, void* d_ws, size_t ws_size,
                              hipStream_t stream)
{
    const int*   ids    = (const int*)  d_in[0];
    const float* emb    = (const float*)d_in[1];
    const float* W_ih0  = (const float*)d_in[2];
    const float* W_hh0  = (const float*)d_in[3];
    const float* b_ih0  = (const float*)d_in[4];
    const float* b_hh0  = (const float*)d_in[5];
    const float* W_ih1  = (const float*)d_in[6];
    const float* W_hh1  = (const float*)d_in[7];
    const float* b_ih1  = (const float*)d_in[8];
    const float* b_hh1  = (const float*)d_in[9];
    const float* W_head = (const float*)d_in[10];

    float* out = (float*)d_out;
    const int M = B_DIM * T_DIM;              // 65536
    // d_out doubles as scratch for pre0/pre1 (dead by the time head GEMM
    // rewrites it). h1/h2 share one 64 MB region of d_ws.
    float* pre0 = out;                        // 16.8M floats
    float* pre1 = out + (size_t)M * D_DIM;    // second half of d_out
    float* h1   = (float*)d_ws;               // 16.8M floats (needs 64 MB ws)
    float* h2   = h1;                          // h1 dead once pre1 is built

    dim3 blk(256);

    // pre0 = emb[ids] @ W_ih0^T + (b_ih0 + b_hh0)
    gemm_bt<<<dim3(M / 128, D_DIM / 128), blk, 0, stream>>>(
        nullptr, W_ih0, pre0, b_ih0, b_hh0, ids, emb, M, D_DIM, D_DIM);
    // layer-0 recurrence
    rnn_scan<<<dim3(B_DIM), blk, 0, stream>>>(pre0, W_hh0, h1);
    // pre1 = h1 @ W_ih1^T + (b_ih1 + b_hh1)
    gemm_bt<<<dim3(M / 128, D_DIM / 128), blk, 0, stream>>>(
        h1, W_ih1, pre1, b_ih1, b_hh1, nullptr, nullptr, M, D_DIM, D_DIM);
    // layer-1 recurrence (h2 overwrites h1 region; h1 no longer needed)
    rnn_scan<<<dim3(B_DIM), blk, 0, stream>>>(pre1, W_hh1, h2);
    // logits = h2 @ W_head^T   (rewrites all of d_out)
    gemm_bt<<<dim3(M / 128, S_DIM / 128), blk, 0, stream>>>(
        h2, W_head, out, nullptr, nullptr, nullptr, nullptr, M, S_DIM, D_DIM);
}

// Round 2
// 1623.545 us; speedup vs baseline: 1.8647x; 1.8647x over previous
//
#include <hip/hip_runtime.h>
#include <cstdint>
#include <cstddef>

#define D_DIM 256
#define T_DIM 512
#define B_DIM 128
#define S_DIM 512

typedef float v2f __attribute__((ext_vector_type(2)));

// C[M,N] = A[M,K] @ B[N,K]^T (+bias1+bias2). If ids!=nullptr, A row m = emb[ids[m]].
// 256 threads, 128x128 tile, 8x8 microtile, K-chunk 16.
__global__ __launch_bounds__(256, 2)
void gemm_bt(const float* __restrict__ A, const float* __restrict__ Bm,
             float* __restrict__ C,
             const float* __restrict__ bias1, const float* __restrict__ bias2,
             const int* __restrict__ ids, const float* __restrict__ emb,
             int M, int N, int K)
{
    __shared__ float As[16][128];
    __shared__ float Bs[16][128];
    const int tid = threadIdx.x;
    const int m0 = blockIdx.x * 128;
    const int n0 = blockIdx.y * 128;
    const int tx = tid & 15;   // N direction
    const int ty = tid >> 4;   // M direction

    float acc[8][8];
#pragma unroll
    for (int i = 0; i < 8; ++i)
#pragma unroll
        for (int j = 0; j < 8; ++j) acc[i][j] = 0.0f;

    for (int kc = 0; kc < K; kc += 16) {
#pragma unroll
        for (int p = 0; p < 2; ++p) {
            int f   = tid + p * 256;   // 0..511
            int row = f >> 2;          // 0..127
            int kq  = f & 3;           // which float4 in the 16-wide k chunk
            int gm = m0 + row;
            const float* arow = ids ? (emb + (size_t)ids[gm] * K)
                                    : (A + (size_t)gm * K);
            float4 v = *(const float4*)(arow + kc + kq * 4);
            As[kq * 4 + 0][row] = v.x;
            As[kq * 4 + 1][row] = v.y;
            As[kq * 4 + 2][row] = v.z;
            As[kq * 4 + 3][row] = v.w;
            const float* brow = Bm + (size_t)(n0 + row) * K;
            float4 w = *(const float4*)(brow + kc + kq * 4);
            Bs[kq * 4 + 0][row] = w.x;
            Bs[kq * 4 + 1][row] = w.y;
            Bs[kq * 4 + 2][row] = w.z;
            Bs[kq * 4 + 3][row] = w.w;
        }
        __syncthreads();
#pragma unroll
        for (int k = 0; k < 16; ++k) {
            float a[8], b[8];
            *(float4*)&a[0] = *(const float4*)&As[k][ty * 8];
            *(float4*)&a[4] = *(const float4*)&As[k][ty * 8 + 4];
            *(float4*)&b[0] = *(const float4*)&Bs[k][tx * 8];
            *(float4*)&b[4] = *(const float4*)&Bs[k][tx * 8 + 4];
#pragma unroll
            for (int i = 0; i < 8; ++i)
#pragma unroll
                for (int j = 0; j < 8; ++j) acc[i][j] += a[i] * b[j];
        }
        __syncthreads();
    }

    float bv[8];
#pragma unroll
    for (int j = 0; j < 8; ++j) {
        int gn = n0 + tx * 8 + j;
        float v = 0.0f;
        if (bias1) v += bias1[gn];
        if (bias2) v += bias2[gn];
        bv[j] = v;
    }
#pragma unroll
    for (int i = 0; i < 8; ++i) {
        int gm = m0 + ty * 8 + i;
        float* crow = C + (size_t)gm * N + n0 + tx * 8;
        float4 v0 = make_float4(acc[i][0] + bv[0], acc[i][1] + bv[1],
                                acc[i][2] + bv[2], acc[i][3] + bv[3]);
        float4 v1 = make_float4(acc[i][4] + bv[4], acc[i][5] + bv[5],
                                acc[i][6] + bv[6], acc[i][7] + bv[7]);
        *(float4*)(crow)     = v0;
        *(float4*)(crow + 4) = v1;
    }
}

// Elman recurrence, v2. One block (512 threads) per batch element.
// Threads 2u and 2u+1 (adjacent lanes, SAME wave) own unit u; each holds
// half of W_hh[u,:] in 32 float4 = 128 VGPRs (promotable under the 256-VGPR
// cap of __launch_bounds__(512,2) -- R1's 256-VGPR ask spilled at 144).
// Partial dots combine via __shfl_xor(p,1) (no LDS reduce). h ping-pongs
// between two LDS buffers -> ONE barrier per step. Packed-fp32 FMA via
// float2 ext vectors, 4 independent accumulators (chain depth 16).
__global__ __launch_bounds__(512, 2)
void rnn_scan(const float* __restrict__ pre, const float* __restrict__ Whh,
              float* __restrict__ hout)
{
    const int b   = blockIdx.x;
    const int tid = threadIdx.x;   // 0..511
    const int u   = tid >> 1;      // unit 0..255
    const int q   = tid & 1;       // k-half: [0,128) or [128,256)

    float4 wv[32];
    const float4* wrow = (const float4*)(Whh + (size_t)u * D_DIM + q * 128);
#pragma unroll
    for (int j = 0; j < 32; ++j) wv[j] = wrow[j];

    __shared__ float hs[2][D_DIM];
    if (tid < D_DIM) hs[0][tid] = 0.0f;

    const float* prow  = pre  + (size_t)b * T_DIM * D_DIM;
    float*       horow = hout + (size_t)b * T_DIM * D_DIM;

    float curp = (q == 0) ? prow[u] : 0.0f;   // even lanes carry pre_t
    __syncthreads();

    for (int t = 0; t < T_DIM; ++t) {
        // prefetch next step's pre (even lanes only)
        float nxtp = 0.0f;
        if (q == 0 && t + 1 < T_DIM) nxtp = prow[(size_t)(t + 1) * D_DIM + u];

        const float4* hv = (const float4*)(&hs[t & 1][0] + q * 128);
        v2f a0 = {0.f, 0.f}, a1 = {0.f, 0.f}, a2 = {0.f, 0.f}, a3 = {0.f, 0.f};
#pragma unroll
        for (int j = 0; j < 32; ++j) {
            float4 h4 = hv[j];
            float4 w4 = wv[j];
            v2f wlo = {w4.x, w4.y}, whi = {w4.z, w4.w};
            v2f hlo = {h4.x, h4.y}, hhi = {h4.z, h4.w};
            if (j & 1) {
                a2 = __builtin_elementwise_fma(wlo, hlo, a2);
                a3 = __builtin_elementwise_fma(whi, hhi, a3);
            } else {
                a0 = __builtin_elementwise_fma(wlo, hlo, a0);
                a1 = __builtin_elementwise_fma(whi, hhi, a1);
            }
        }
        v2f s = (a0 + a1) + (a2 + a3);
        float p = s.x + s.y;
        float o = __shfl_xor(p, 1);   // partner lane's half-dot

        if (q == 0) {
            float hn = tanhf(p + o + curp);
            hs[(t + 1) & 1][u] = hn;
            horow[(size_t)t * D_DIM + u] = hn;
        }
        curp = nxtp;
        __syncthreads();   // publish hs[(t+1)&1] before next step's reads
    }
}

extern "C" void kernel_launch(void* const* d_in, const int* in_sizes, int n_in,
                              void* d_out, int out_size, void* d_ws, size_t ws_size,
                              hipStream_t stream)
{
    const int*   ids    = (const int*)  d_in[0];
    const float* emb    = (const float*)d_in[1];
    const float* W_ih0  = (const float*)d_in[2];
    const float* W_hh0  = (const float*)d_in[3];
    const float* b_ih0  = (const float*)d_in[4];
    const float* b_hh0  = (const float*)d_in[5];
    const float* W_ih1  = (const float*)d_in[6];
    const float* W_hh1  = (const float*)d_in[7];
    const float* b_ih1  = (const float*)d_in[8];
    const float* b_hh1  = (const float*)d_in[9];
    const float* W_head = (const float*)d_in[10];

    float* out = (float*)d_out;
    const int M = B_DIM * T_DIM;              // 65536
    float* pre0 = out;                        // d_out doubles as scratch
    float* pre1 = out + (size_t)M * D_DIM;
    float* h1   = (float*)d_ws;               // 64 MB of ws
    float* h2   = h1;

    // pre0 = emb[ids] @ W_ih0^T + (b_ih0 + b_hh0)
    gemm_bt<<<dim3(M / 128, D_DIM / 128), dim3(256), 0, stream>>>(
        nullptr, W_ih0, pre0, b_ih0, b_hh0, ids, emb, M, D_DIM, D_DIM);
    // layer-0 recurrence
    rnn_scan<<<dim3(B_DIM), dim3(512), 0, stream>>>(pre0, W_hh0, h1);
    // pre1 = h1 @ W_ih1^T + (b_ih1 + b_hh1)
    gemm_bt<<<dim3(M / 128, D_DIM / 128), dim3(256), 0, stream>>>(
        h1, W_ih1, pre1, b_ih1, b_hh1, nullptr, nullptr, M, D_DIM, D_DIM);
    // layer-1 recurrence
    rnn_scan<<<dim3(B_DIM), dim3(512), 0, stream>>>(pre1, W_hh1, h2);
    // logits = h2 @ W_head^T
    gemm_bt<<<dim3(M / 128, S_DIM / 128), dim3(256), 0, stream>>>(
        h2, W_head, out, nullptr, nullptr, nullptr, nullptr, M, S_DIM, D_DIM);
}